// Round 4
// baseline (369.985 us; speedup 1.0000x reference)
//
#include <hip/hip_runtime.h>
#include <math.h>

// PixPro fused masked all-pairs cosine loss, MI355X (gfx950).
// B=2048, C=256, H=W=7 -> P=49 pixels.
// out[b] = -(1/2401) * sum_{p,q} wt[p][q] * dot(base_p, mom_q)/max(nb_p*nm_q, eps)
// wt[p][q] = [base_A[p,q]==1] + [moment_A[q,p]==1]   (loss-term fusion).
//
// R4: scalar-broadcast structure (SGEMV pattern).
//   - 1 batch per 256-thread block; wave w owns channels [64w, 64w+64).
//   - lane = q (mom pixel, 49 active); acc[p] per lane, p = 0..48.
//   - base row base[c, 0..48] is WAVE-UNIFORM -> loaded via the scalar pipe
//     (s_load_dwordx16) and consumed as the SGPR operand of v_fma_f32.
//     Address uniformity is forced with __builtin_amdgcn_readfirstlane(wave).
//   - vector memory: 2 coalesced global_load_dword per channel per wave
//     (mom[c,q] for the dots+mom-norm, base[c,lane] for the base-norm).
//   - macro-iteration = 4 channels = 49 uniform float4 (196 floats, stream is
//     16B-aligned since 49*64*4B = 12544B) + 4+4 lane loads + 196+8 FMA.
//   - cross-wave combine via LDS atomics (epilogue only), then cosine pass.

constexpr int NBATCH = 2048;
constexpr int NC     = 256;
constexpr int NP     = 49;
constexpr int FPB    = NC * NP;   // 12544 floats per feature per batch
constexpr float EPS  = 1e-6f;

__global__ __launch_bounds__(256, 6)
void pixpro_kernel(const float* __restrict__ gbase,
                   const float* __restrict__ gmom,
                   const int*   __restrict__ A1,
                   const int*   __restrict__ A2,
                   float*       __restrict__ out)
{
    __shared__ float dots[NP * NP];
    __shared__ float bn[NP];
    __shared__ float mn[NP];
    __shared__ float red[4];

    const int tid  = threadIdx.x;
    const int lane = tid & 63;
    const int b    = blockIdx.x;
    // provably wave-uniform wave id -> scalar (s_load) addressing below
    const int wave = __builtin_amdgcn_readfirstlane(tid >> 6);

    for (int t = tid; t < NP * NP; t += 256) dots[t] = 0.0f;
    if (tid < NP) { bn[tid] = 0.0f; mn[tid] = 0.0f; }
    __syncthreads();

    const int q = (lane < NP) ? lane : NP - 1;   // lanes 49..63 duplicate q=48

    const float* ub  = gbase + (size_t)b * FPB + wave * (64 * NP); // uniform stream
    const float* pm  = gmom  + (size_t)b * FPB + wave * (64 * NP) + q;
    const float* pbn = gbase + (size_t)b * FPB + wave * (64 * NP) + q;

    float acc[NP];
    #pragma unroll
    for (int p = 0; p < NP; ++p) acc[p] = 0.0f;
    float nrmB = 0.0f, nrmM = 0.0f;

    for (int m = 0; m < 16; ++m) {               // 16 macro-iters x 4 channels
        const float4* uc = (const float4*)(ub + m * (4 * NP));  // uniform, 16B-aligned

        float vm[4], vb[4];
        #pragma unroll
        for (int j = 0; j < 4; ++j) {
            vm[j] = pm [(m * 4 + j) * NP];       // coalesced lanes 0..48
            vb[j] = pbn[(m * 4 + j) * NP];
        }
        #pragma unroll
        for (int j = 0; j < 4; ++j) {
            nrmM = fmaf(vm[j], vm[j], nrmM);
            nrmB = fmaf(vb[j], vb[j], nrmB);
        }

        // 49 uniform float4 chunks cover exactly 4 channels (196 floats).
        // chunk t, element e -> global idx g = 4t+e -> c = g/49, p = g%49
        // (compile-time after unroll; acc[] never dynamically indexed).
        #pragma unroll
        for (int t = 0; t < 49; ++t) {
            const float4 ch = uc[t];             // expect s_load_dwordx4/x16
            const float v[4] = { ch.x, ch.y, ch.z, ch.w };
            #pragma unroll
            for (int e = 0; e < 4; ++e) {
                const int g = 4 * t + e;
                const int c = g / NP;
                const int p = g - c * NP;
                acc[p] = fmaf(v[e], vm[c], acc[p]);
            }
        }
    }

    // ---- cross-wave combine (lanes 49..63 are duplicates: excluded) ----
    if (lane < NP) {
        #pragma unroll
        for (int p = 0; p < NP; ++p)
            atomicAdd(&dots[p * NP + q], acc[p]);
        atomicAdd(&mn[q], nrmM);
        atomicAdd(&bn[q], nrmB);   // lane index served as p for the base norm
    }
    __syncthreads();

    // ---- cosine + mask + reduction over the 2401 cells ----
    float sum = 0.0f;
    for (int e = tid; e < NP * NP; e += 256) {
        int p = e / NP, qq = e - p * NP;
        float w = (A1[e] == 1 ? 1.0f : 0.0f) + (A2[qq * NP + p] == 1 ? 1.0f : 0.0f);
        float den = fmaxf(sqrtf(bn[p]) * sqrtf(mn[qq]), EPS);
        sum += w * dots[e] / den;
    }

    #pragma unroll
    for (int s = 32; s; s >>= 1) sum += __shfl_xor(sum, s, 64);
    if (lane == 0) red[tid >> 6] = sum;
    __syncthreads();
    if (tid == 0) out[b] = (red[0] + red[1] + red[2] + red[3]) * (-1.0f / 2401.0f);
}

extern "C" void kernel_launch(void* const* d_in, const int* in_sizes, int n_in,
                              void* d_out, int out_size, void* d_ws, size_t ws_size,
                              hipStream_t stream)
{
    (void)in_sizes; (void)n_in; (void)d_ws; (void)ws_size; (void)out_size;
    const float* base = (const float*)d_in[0];
    const float* mom  = (const float*)d_in[1];
    const int*   A1   = (const int*)d_in[2];
    const int*   A2   = (const int*)d_in[3];
    float*       out  = (float*)d_out;

    pixpro_kernel<<<NBATCH, 256, 0, stream>>>(base, mom, A1, A2, out);
}

// Round 5
// 345.576 us; speedup vs baseline: 1.0706x; 1.0706x over previous
//
#include <hip/hip_runtime.h>
#include <math.h>

// PixPro fused masked all-pairs cosine loss, MI355X (gfx950).
// B=2048, C=256, H=W=7 -> P=49 pixels.
// out[b] = -(1/2401) * sum_{p,q} wt[p][q] * dot(base_p, mom_q)/max(nb_p*nm_q, eps)
// wt[p][q] = [base_A[p,q]==1] + [moment_A[q,p]==1]   (loss-term fusion).
//
// R5: scalar-pipe broadcast (SGEMV pattern), FORCED via inline-asm s_load.
//   - 1 batch per 256-thread block; wave w owns channels [64w, 64w+64).
//   - lane = q (49 active); acc[p] in VGPRs (49).
//   - base row base[c, 0..48] is wave-uniform: loaded with s_load_dwordx16
//     x3 + s_load_dword into SGPRs (inline asm, since the compiler refuses
//     to select SMEM for uniform global loads here — R4 evidence), consumed
//     directly as the SGPR src0 of v_fmac_f32.
//   - vector memory: 2 coalesced global_load_dword per channel per wave
//     (mom[c,q] and base[c,lane] for the norms), 1-channel prefetch.
//   - SMEM returns are out-of-order -> only lgkmcnt(0) is a safe wait;
//     per-channel round-trips are hidden by TLP (32 waves/CU of work).
//   - cross-wave combine via LDS f32 atomics (epilogue only), then cosine.
//   - NO __launch_bounds__ min-waves cap: R2/R4 died on forced spills.

constexpr int NBATCH = 2048;
constexpr int NC     = 256;
constexpr int NP     = 49;
constexpr int FPB    = NC * NP;   // 12544 floats per feature per batch
constexpr float EPS  = 1e-6f;

typedef __attribute__((ext_vector_type(16))) float f32x16;

__global__ __launch_bounds__(256)
void pixpro_kernel(const float* __restrict__ gbase,
                   const float* __restrict__ gmom,
                   const int*   __restrict__ A1,
                   const int*   __restrict__ A2,
                   float*       __restrict__ out)
{
    __shared__ float dots[NP * NP];
    __shared__ float bn[NP];
    __shared__ float mn[NP];
    __shared__ float red[4];

    const int tid  = threadIdx.x;
    const int lane = tid & 63;
    const int b    = blockIdx.x;
    const int wave = __builtin_amdgcn_readfirstlane(tid >> 6);  // uniform

    for (int t = tid; t < NP * NP; t += 256) dots[t] = 0.0f;
    if (tid < NP) { bn[tid] = 0.0f; mn[tid] = 0.0f; }
    __syncthreads();

    const int q = (lane < NP) ? lane : NP - 1;   // lanes 49..63 duplicate q=48

    const float* ub = gbase + (size_t)b * FPB + wave * (64 * NP);      // uniform stream
    const float* pm = gmom  + (size_t)b * FPB + wave * (64 * NP) + q;  // per-lane
    const float* pb = gbase + (size_t)b * FPB + wave * (64 * NP) + q;  // per-lane

    float acc[NP];
    #pragma unroll
    for (int p = 0; p < NP; ++p) acc[p] = 0.0f;
    float nrmB = 0.0f, nrmM = 0.0f;

    float vm = pm[0];
    float vb = pb[0];

    for (int c = 0; c < 64; ++c) {
        const float* uc = ub + c * NP;           // uniform, 4B-aligned
        f32x16 s0, s1, s2; float s3;
        asm volatile("s_load_dwordx16 %0, %1, 0x0"  : "=s"(s0) : "s"(uc));
        asm volatile("s_load_dwordx16 %0, %1, 0x40" : "=s"(s1) : "s"(uc));
        asm volatile("s_load_dwordx16 %0, %1, 0x80" : "=s"(s2) : "s"(uc));
        asm volatile("s_load_dword    %0, %1, 0xc0" : "=s"(s3) : "s"(uc));

        // prefetch next channel's lane values (vmcnt path, independent of lgkm)
        float vm_n = 0.0f, vb_n = 0.0f;
        if (c < 63) { vm_n = pm[(c + 1) * NP]; vb_n = pb[(c + 1) * NP]; }

        nrmM = fmaf(vm, vm, nrmM);
        nrmB = fmaf(vb, vb, nrmB);

        // SMEM results ready only after lgkmcnt(0); tie regs so uses follow.
        asm volatile("s_waitcnt lgkmcnt(0)"
                     : "+s"(s0), "+s"(s1), "+s"(s2), "+s"(s3));

        #pragma unroll
        for (int p = 0; p < 16; ++p) acc[p]      = fmaf(s0[p], vm, acc[p]);
        #pragma unroll
        for (int p = 0; p < 16; ++p) acc[16 + p] = fmaf(s1[p], vm, acc[16 + p]);
        #pragma unroll
        for (int p = 0; p < 16; ++p) acc[32 + p] = fmaf(s2[p], vm, acc[32 + p]);
        acc[48] = fmaf(s3, vm, acc[48]);

        vm = vm_n; vb = vb_n;
    }

    // ---- cross-wave combine (lanes 49..63 are duplicates: excluded) ----
    if (lane < NP) {
        #pragma unroll
        for (int p = 0; p < NP; ++p)
            atomicAdd(&dots[p * NP + q], acc[p]);
        atomicAdd(&mn[q], nrmM);
        atomicAdd(&bn[lane], nrmB);   // lane index serves as p here
    }
    __syncthreads();

    // norms -> sqrt in place
    if (tid < NP) { bn[tid] = sqrtf(bn[tid]); mn[tid] = sqrtf(mn[tid]); }
    __syncthreads();

    // ---- cosine + mask + reduction over the 2401 cells ----
    float sum = 0.0f;
    for (int e = tid; e < NP * NP; e += 256) {
        int p = e / NP, qq = e - p * NP;
        float w = (A1[e] == 1 ? 1.0f : 0.0f) + (A2[qq * NP + p] == 1 ? 1.0f : 0.0f);
        float den = fmaxf(bn[p] * mn[qq], EPS);
        sum += w * dots[e] / den;
    }

    #pragma unroll
    for (int s = 32; s; s >>= 1) sum += __shfl_xor(sum, s, 64);
    if (lane == 0) red[tid >> 6] = sum;
    __syncthreads();
    if (tid == 0) out[b] = (red[0] + red[1] + red[2] + red[3]) * (-1.0f / 2401.0f);
}

extern "C" void kernel_launch(void* const* d_in, const int* in_sizes, int n_in,
                              void* d_out, int out_size, void* d_ws, size_t ws_size,
                              hipStream_t stream)
{
    (void)in_sizes; (void)n_in; (void)d_ws; (void)ws_size; (void)out_size;
    const float* base = (const float*)d_in[0];
    const float* mom  = (const float*)d_in[1];
    const int*   A1   = (const int*)d_in[2];
    const int*   A2   = (const int*)d_in[3];
    float*       out  = (float*)d_out;

    pixpro_kernel<<<NBATCH, 256, 0, stream>>>(base, mom, A1, A2, out);
}

// Round 6
// 274.902 us; speedup vs baseline: 1.3459x; 1.2571x over previous
//
#include <hip/hip_runtime.h>
#include <math.h>

// PixPro fused masked all-pairs cosine loss, MI355X (gfx950).
// B=2048, C=256, H=W=7 -> P=49 pixels.
// out[b] = -(1/2401) * sum_{p,q} wt[p][q] * dot(base_p, mom_q)/max(nb_p*nm_q, eps)
// wt[p][q] = [base_A[p,q]==1] + [moment_A[q,p]==1]   (loss-term fusion).
//
// R6: MFMA. Per batch, D[49x49] = base^T(49x256) . mom(256x49) is a GEMM.
// fp32 -> (f16 hi + f16 lo) split; D = Ah.Bh + Ah.Bl + Al.Bh in fp32 acc
// (missing lo.lo term ~2^-22 relative — far inside threshold).
// v_mfma_f32_16x16x16_f16, 4x4 tiles of 16 (pad 49->64), slab = 16 ch = 1 K-step.
//   - 1 wave per batch (4 batches / 256-thr block, grid 512) -> NO cross-wave
//     combine; all dot/norm accumulation lives in this wave's acc registers.
//   - staging: flat [c][p] fp32 copy in wave-private LDS (contiguous b128
//     writes, R1-proven); frag reads = 32 ds_read_b32/slab (stride-49 = odd
//     -> bank-clean), each element cvt'd to hi/lo exactly once.
//   - norms FREE via MFMA: A-frag and B-frag lane->element maps are identical
//     (m=lane&15,k=4*quad+i vs n=lane&15,k=4*quad+i), so the base A-frag regs
//     serve as B-frag of base: diag of base^T.base = sum x^2. Same for mom.
//   - rows 49..63 and the read overrun feed garbage into D cells with
//     m>=49 or n>=49 only (per-cell independence) -> discarded in epilogue.
//   - no __launch_bounds__ min-waves (R2/R4 died on forced spills).

typedef _Float16 half4 __attribute__((ext_vector_type(4)));
typedef float f32x4 __attribute__((ext_vector_type(4)));

constexpr int NBATCH = 2048;
constexpr int NC     = 256;
constexpr int NP     = 49;
constexpr int FPB    = NC * NP;        // 12544 floats per feature per batch
constexpr int SLAB_C = 16;             // channels per slab = K per MFMA step
constexpr int SLABF  = SLAB_C * NP;    // 784 floats per feature per slab
constexpr int NSLAB  = NC / SLAB_C;    // 16
constexpr int WBUF   = 2 * SLABF + 64; // base | mom | guard (read-overrun pad)
constexpr float EPS  = 1e-6f;

__device__ __forceinline__ void split16(float x, _Float16& h, _Float16& l) {
    h = (_Float16)x;
    l = (_Float16)(x - (float)h);
}

__device__ __forceinline__ float vsel(f32x4 v, int r) {
    float x = v[0];
    x = (r == 1) ? v[1] : x;
    x = (r == 2) ? v[2] : x;
    x = (r == 3) ? v[3] : x;
    return x;
}

__global__ __launch_bounds__(256)
void pixpro_kernel(const float* __restrict__ gbase,
                   const float* __restrict__ gmom,
                   const int*   __restrict__ A1,
                   const int*   __restrict__ A2,
                   float*       __restrict__ out)
{
    __shared__ float wt[NP * NP];            // combined mask weights (block)
    __shared__ __align__(16) float slab[4][WBUF];  // wave-private staging
    __shared__ float bnorm[4][64];           // per-wave sum base^2 (by p)
    __shared__ float mnorm[4][64];           // per-wave sum mom^2  (by q)

    const int tid  = threadIdx.x;
    const int wave = tid >> 6;
    const int lane = tid & 63;
    const int b    = blockIdx.x * 4 + wave;

    for (int t = tid; t < NP * NP; t += 256) {
        int p = t / NP, q = t - p * NP;
        wt[t] = (A1[t] == 1 ? 1.0f : 0.0f) + (A2[q * NP + p] == 1 ? 1.0f : 0.0f);
    }
    __syncthreads();

    float* sb = slab[wave];
    const float* gb = gbase + (size_t)b * FPB;
    const float* gm = gmom  + (size_t)b * FPB;

    const int m    = lane & 15;      // row (p) within tile for A; col (q) for B/D
    const int quad = lane >> 4;      // k-quad: this lane holds k = 4*quad + i
    const int fbase = 196 * quad + m;  // LDS float index: 49*(4*quad) + m

    // accumulators: 16 dot tiles + 4 base-diag + 4 mom-diag (f32)
    f32x4 accD[4][4], accB[4], accM[4];
    #pragma unroll
    for (int i = 0; i < 4; ++i) {
        #pragma unroll
        for (int j = 0; j < 4; ++j) accD[i][j] = (f32x4)0.0f;
        accB[i] = (f32x4)0.0f;
        accM[i] = (f32x4)0.0f;
    }

    // prefetch slab 0 (196 float4 per feature = 3*64 + 4)
    float4 rb[4] = {}, rm[4] = {};
    {
        const float4* pb = (const float4*)gb;
        const float4* pm = (const float4*)gm;
        rb[0] = pb[lane]; rb[1] = pb[64 + lane]; rb[2] = pb[128 + lane];
        rm[0] = pm[lane]; rm[1] = pm[64 + lane]; rm[2] = pm[128 + lane];
        if (lane < 4) { rb[3] = pb[192 + lane]; rm[3] = pm[192 + lane]; }
    }

    for (int s = 0; s < NSLAB; ++s) {
        // stage current slab: flat [c][p] copy, contiguous b128 writes
        {
            float4* lb = (float4*)sb;
            float4* lm = (float4*)(sb + SLABF);
            lb[lane] = rb[0]; lb[64 + lane] = rb[1]; lb[128 + lane] = rb[2];
            lm[lane] = rm[0]; lm[64 + lane] = rm[1]; lm[128 + lane] = rm[2];
            if (lane < 4) { lb[192 + lane] = rb[3]; lm[192 + lane] = rm[3]; }
        }
        // prefetch next slab
        if (s + 1 < NSLAB) {
            const float4* pb = (const float4*)(gb + (s + 1) * SLABF);
            const float4* pm = (const float4*)(gm + (s + 1) * SLABF);
            rb[0] = pb[lane]; rb[1] = pb[64 + lane]; rb[2] = pb[128 + lane];
            rm[0] = pm[lane]; rm[1] = pm[64 + lane]; rm[2] = pm[128 + lane];
            if (lane < 4) { rb[3] = pb[192 + lane]; rm[3] = pm[192 + lane]; }
        }

        // build fragments: A (base) and B (mom), hi/lo split.
        // element k=4*quad+i of tile t lives at sb[fbase + 49*i + 16*t].
        half4 Ah[4], Al[4], Bh[4], Bl[4];
        #pragma unroll
        for (int t = 0; t < 4; ++t) {
            const int o = fbase + 16 * t;
            float a0 = sb[o], a1 = sb[o + 49], a2 = sb[o + 98], a3 = sb[o + 147];
            float c0 = sb[SLABF + o], c1 = sb[SLABF + o + 49],
                  c2 = sb[SLABF + o + 98], c3 = sb[SLABF + o + 147];
            _Float16 h, l;
            split16(a0, h, l); Ah[t][0] = h; Al[t][0] = l;
            split16(a1, h, l); Ah[t][1] = h; Al[t][1] = l;
            split16(a2, h, l); Ah[t][2] = h; Al[t][2] = l;
            split16(a3, h, l); Ah[t][3] = h; Al[t][3] = l;
            split16(c0, h, l); Bh[t][0] = h; Bl[t][0] = l;
            split16(c1, h, l); Bh[t][1] = h; Bl[t][1] = l;
            split16(c2, h, l); Bh[t][2] = h; Bl[t][2] = l;
            split16(c3, h, l); Bh[t][3] = h; Bl[t][3] = l;
        }

        // dot tiles: D[p][q] = base^T . mom  (3-pass hi/lo)
        #pragma unroll
        for (int mt = 0; mt < 4; ++mt) {
            #pragma unroll
            for (int nt = 0; nt < 4; ++nt) {
                accD[mt][nt] = __builtin_amdgcn_mfma_f32_16x16x16f16(Ah[mt], Bh[nt], accD[mt][nt], 0, 0, 0);
                accD[mt][nt] = __builtin_amdgcn_mfma_f32_16x16x16f16(Ah[mt], Bl[nt], accD[mt][nt], 0, 0, 0);
                accD[mt][nt] = __builtin_amdgcn_mfma_f32_16x16x16f16(Al[mt], Bh[nt], accD[mt][nt], 0, 0, 0);
            }
        }
        // norm (diag) tiles: base^T.base and mom^T.mom — A-frag regs reused
        // as B operand (identical lane->element map).
        #pragma unroll
        for (int t = 0; t < 4; ++t) {
            accB[t] = __builtin_amdgcn_mfma_f32_16x16x16f16(Ah[t], Ah[t], accB[t], 0, 0, 0);
            accB[t] = __builtin_amdgcn_mfma_f32_16x16x16f16(Ah[t], Al[t], accB[t], 0, 0, 0);
            accB[t] = __builtin_amdgcn_mfma_f32_16x16x16f16(Al[t], Ah[t], accB[t], 0, 0, 0);
            accM[t] = __builtin_amdgcn_mfma_f32_16x16x16f16(Bh[t], Bh[t], accM[t], 0, 0, 0);
            accM[t] = __builtin_amdgcn_mfma_f32_16x16x16f16(Bh[t], Bl[t], accM[t], 0, 0, 0);
            accM[t] = __builtin_amdgcn_mfma_f32_16x16x16f16(Bl[t], Bh[t], accM[t], 0, 0, 0);
        }
    }

    // ---- epilogue (fully wave-local) ----
    // D layout: col=lane&15, row=4*quad+reg  (tile offsets +16*{mt,nt}).
    // diag cell (p,p): lanes where 4*quad+reg == col, reg = col-4*quad.
    float* bn = bnorm[wave];
    float* mn = mnorm[wave];
    {
        const int r0 = m - 4 * quad;
        if (r0 >= 0 && r0 < 4) {
            #pragma unroll
            for (int t = 0; t < 4; ++t) {
                bn[16 * t + m] = vsel(accB[t], r0);
                mn[16 * t + m] = vsel(accM[t], r0);
            }
        }
    }
    __syncthreads();   // orders the per-wave LDS norm writes vs reads below

    float sum = 0.0f;
    #pragma unroll
    for (int nt = 0; nt < 4; ++nt) {
        const int qq = 16 * nt + m;
        if (qq < NP) {
            const float nmv = sqrtf(mn[qq]);
            #pragma unroll
            for (int mt = 0; mt < 4; ++mt) {
                #pragma unroll
                for (int r = 0; r < 4; ++r) {
                    const int p = 16 * mt + 4 * quad + r;
                    if (p < NP) {
                        const float nbv = sqrtf(bn[p]);
                        const float d   = accD[mt][nt][r];
                        sum += wt[p * NP + qq] * d / fmaxf(nbv * nmv, EPS);
                    }
                }
            }
        }
    }

    #pragma unroll
    for (int sh = 32; sh; sh >>= 1) sum += __shfl_xor(sum, sh, 64);
    if (lane == 0) out[b] = sum * (-1.0f / 2401.0f);
}

extern "C" void kernel_launch(void* const* d_in, const int* in_sizes, int n_in,
                              void* d_out, int out_size, void* d_ws, size_t ws_size,
                              hipStream_t stream)
{
    (void)in_sizes; (void)n_in; (void)d_ws; (void)ws_size; (void)out_size;
    const float* base = (const float*)d_in[0];
    const float* mom  = (const float*)d_in[1];
    const int*   A1   = (const int*)d_in[2];
    const int*   A2   = (const int*)d_in[3];
    float*       out  = (float*)d_out;

    pixpro_kernel<<<NBATCH / 4, 256, 0, stream>>>(base, mom, A1, A2, out);
}